// Round 2
// baseline (498.908 us; speedup 1.0000x reference)
//
#include <hip/hip_runtime.h>

// Problem constants (from reference): B=16, F=257, M=6, T=1000, N_ITER=2
#define BQ 16
#define FQ 257
#define MQ 6
#define TQ 1000
#define T4Q 250                  // TQ/4 float4 columns per row (4000B rows, 16B aligned)
#define BFQ (BQ * FQ)            // 4112 independent (b,f) problems
#define FMTQ (FQ * MQ * TQ)      // 1,542,000  (divisor for per-batch scale mean)

__device__ __forceinline__ float wave_sum(float v) {
    v += __shfl_xor(v, 1);  v += __shfl_xor(v, 2);  v += __shfl_xor(v, 4);
    v += __shfl_xor(v, 8);  v += __shfl_xor(v, 16); v += __shfl_xor(v, 32);
    return v;
}

// ---------------------------------------------------------------------------
// K1: per (b,f):
//   V[k][m][n] = (1/T) sum_t r[k,t] * x[m,t] * conj(x[n,t])  + eps on diagonal
//   C[m][n]    =        sum_t x[m,t] * conj(x[n,t])   (for trace-based scale)
// 4 waves per (b,f); 21 Hermitian (m<=n) pairs partitioned at COMPILE TIME so
// each wave holds <=70 accumulators (no spill). Waves write disjoint V/C
// entries -> no cross-wave reduction needed.
// R1: t-loop vectorized as float4 (250 cols) — 4x fewer VMEM instructions.
// Also zeroes the 32 scale accumulators (block 0) so k_zero launch is gone.
// Pair partition (21 Hermitian pairs, DO NOT EDIT without checking coverage):
//   W0: (0,0)(0,1)(0,2)(1,1)(1,2)(2,2)   rows {0,1,2}
//   W1: (3,3)(3,4)(3,5)(4,4)(4,5)(5,5)   rows {3,4,5}
//   W2: (0,3)(0,4)(0,5)(1,3)(1,4)        cross part 1
//   W3: (1,5)(2,3)(2,4)(2,5)             cross part 2
// ---------------------------------------------------------------------------
template<int W> struct PL;
template<> struct PL<0> { static constexpr int np = 6;
    static constexpr int pm[6] = {0,0,0,1,1,2};
    static constexpr int pn[6] = {0,1,2,1,2,2}; };
template<> struct PL<1> { static constexpr int np = 6;
    static constexpr int pm[6] = {3,3,3,4,4,5};
    static constexpr int pn[6] = {3,4,5,4,5,5}; };
template<> struct PL<2> { static constexpr int np = 5;
    static constexpr int pm[6] = {0,0,0,1,1,0};
    static constexpr int pn[6] = {3,4,5,3,4,0}; };
template<> struct PL<3> { static constexpr int np = 4;
    static constexpr int pm[6] = {1,2,2,2,0,0};
    static constexpr int pn[6] = {5,3,4,5,0,0}; };

template<int W> __device__ constexpr unsigned rowMaskFn() {
    unsigned msk = 0;
    for (int p = 0; p < PL<W>::np; p++) {
        msk |= 1u << PL<W>::pm[p];
        msk |= 1u << PL<W>::pn[p];
    }
    return msk;
}

template<int W>
__device__ __forceinline__ void stats_work(
    int bf, int lane, const float* __restrict__ rp,
    const float* __restrict__ xrp, const float* __restrict__ xip,
    float* __restrict__ V, float* __restrict__ Cw)
{
    constexpr int NP = PL<W>::np;
    constexpr unsigned rowmask = rowMaskFn<W>();

    float Vre[NP][6], Vim[NP][6], Cre[NP], Cim[NP];
#pragma unroll
    for (int p = 0; p < NP; p++) {
        Cre[p] = 0.0f; Cim[p] = 0.0f;
#pragma unroll
        for (int k = 0; k < 6; k++) { Vre[p][k] = 0.0f; Vim[p][k] = 0.0f; }
    }

    const float4* rp4  = reinterpret_cast<const float4*>(rp);
    const float4* xrp4 = reinterpret_cast<const float4*>(xrp);
    const float4* xip4 = reinterpret_cast<const float4*>(xip);

#pragma unroll 1
    for (int i = lane; i < T4Q; i += 64) {
        float rr[6][4], ar[6][4], ai[6][4];
#pragma unroll
        for (int k = 0; k < 6; k++) {
            const float4 v = rp4[k * T4Q + i];
            rr[k][0] = v.x; rr[k][1] = v.y; rr[k][2] = v.z; rr[k][3] = v.w;
        }
#pragma unroll
        for (int row = 0; row < 6; row++) {
            if (rowmask & (1u << row)) {           // compile-time folded
                const float4 a = xrp4[row * T4Q + i];
                ar[row][0] = a.x; ar[row][1] = a.y; ar[row][2] = a.z; ar[row][3] = a.w;
                const float4 b = xip4[row * T4Q + i];
                ai[row][0] = b.x; ai[row][1] = b.y; ai[row][2] = b.z; ai[row][3] = b.w;
            }
        }
#pragma unroll
        for (int e = 0; e < 4; e++) {
#pragma unroll
            for (int p = 0; p < NP; p++) {
                const int m = PL<W>::pm[p], n = PL<W>::pn[p];
                if (m == n) {
                    const float pr = ar[m][e] * ar[m][e] + ai[m][e] * ai[m][e];
                    Cre[p] += pr;
#pragma unroll
                    for (int k = 0; k < 6; k++) Vre[p][k] += rr[k][e] * pr;
                } else {
                    const float pr = ar[m][e] * ar[n][e] + ai[m][e] * ai[n][e];
                    const float pi = ai[m][e] * ar[n][e] - ar[m][e] * ai[n][e];
                    Cre[p] += pr;  Cim[p] += pi;
#pragma unroll
                    for (int k = 0; k < 6; k++) {
                        Vre[p][k] += rr[k][e] * pr;
                        Vim[p][k] += rr[k][e] * pi;
                    }
                }
            }
        }
    }

    // butterfly-reduce this wave's accumulators
#pragma unroll
    for (int p = 0; p < NP; p++) {
        const int m = PL<W>::pm[p], n = PL<W>::pn[p];
        Cre[p] = wave_sum(Cre[p]);
        if (m != n) Cim[p] = wave_sum(Cim[p]);
#pragma unroll
        for (int k = 0; k < 6; k++) {
            Vre[p][k] = wave_sum(Vre[p][k]);
            if (m != n) Vim[p][k] = wave_sum(Vim[p][k]);
        }
    }

    if (lane == 0) {
        const float invT = 1.0f / (float)TQ;
        float2* Vg = reinterpret_cast<float2*>(V + (size_t)bf * 432);
        float2* Cg = reinterpret_cast<float2*>(Cw + (size_t)bf * 72);
#pragma unroll
        for (int p = 0; p < NP; p++) {
            const int m = PL<W>::pm[p], n = PL<W>::pn[p];
            if (m == n) {
#pragma unroll
                for (int k = 0; k < 6; k++)
                    Vg[k * 36 + m * 6 + m] = make_float2(Vre[p][k] * invT + 1e-6f, 0.0f);
                Cg[m * 6 + m] = make_float2(Cre[p], 0.0f);
            } else {
#pragma unroll
                for (int k = 0; k < 6; k++) {
                    const float re = Vre[p][k] * invT, im = Vim[p][k] * invT;
                    Vg[k * 36 + m * 6 + n] = make_float2(re,  im);
                    Vg[k * 36 + n * 6 + m] = make_float2(re, -im);
                }
                Cg[m * 6 + n] = make_float2(Cre[p],  Cim[p]);
                Cg[n * 6 + m] = make_float2(Cre[p], -Cim[p]);
            }
        }
    }
}

__global__ __launch_bounds__(256) void k_stats(
    const float* __restrict__ r, const float* __restrict__ xre,
    const float* __restrict__ xim, float* __restrict__ V,
    float* __restrict__ Cw, float* __restrict__ S)
{
    const int bf   = blockIdx.x;
    const int w    = threadIdx.x >> 6;
    const int lane = threadIdx.x & 63;
    // fused k_zero: S1[16]|S2[16] contiguous; done before any k_iter atomics
    // (stream order guarantees visibility).
    if (bf == 0 && threadIdx.x < 32) S[threadIdx.x] = 0.0f;
    const float* rp  = r   + (size_t)bf * MQ * TQ;
    const float* xrp = xre + (size_t)bf * MQ * TQ;
    const float* xip = xim + (size_t)bf * MQ * TQ;
    switch (w) {
        case 0:  stats_work<0>(bf, lane, rp, xrp, xip, V, Cw); break;
        case 1:  stats_work<1>(bf, lane, rp, xrp, xip, V, Cw); break;
        case 2:  stats_work<2>(bf, lane, rp, xrp, xip, V, Cw); break;
        default: stats_work<3>(bf, lane, rp, xrp, xip, V, Cw); break;
    }
}

// ---------------------------------------------------------------------------
// K2: one ISS iteration (6 sequential k-steps) + trace(Q C Q^H) partial for
// the per-batch scale. 8 lanes per (b,f): lane kp<6 owns row kp of Q and
// V[kp]; pivot row q broadcast via width-8 shuffles.  (unchanged, verified)
// ---------------------------------------------------------------------------
__global__ __launch_bounds__(256) void k_iter(
    const float* __restrict__ V, const float* __restrict__ Cw,
    const float* __restrict__ Qre_in, const float* __restrict__ Qim_in,
    const float* __restrict__ Sprev,
    float* __restrict__ Qre_out, float* __restrict__ Qim_out,
    float* __restrict__ Sout)
{
    const int gid = blockIdx.x * 256 + threadIdx.x;
    const int g   = gid >> 3;          // (b,f) index
    const int kp  = gid & 7;           // row owned (6,7 inactive dupes of 5)
    if (g >= BFQ) return;
    const int b  = g / FQ;
    const int kk = kp < 6 ? kp : 5;

    const float4* Vp4 = reinterpret_cast<const float4*>(V + (size_t)g * 432 + (size_t)kk * 72);
    const float4* Cp4 = reinterpret_cast<const float4*>(Cw + (size_t)g * 72);
    float4 vb[18], cb[18];
#pragma unroll
    for (int e = 0; e < 18; e++) vb[e] = Vp4[e];
#pragma unroll
    for (int e = 0; e < 18; e++) cb[e] = Cp4[e];

    float Vr[36], Vi[36], Cr[36], Ci[36];
#pragma unroll
    for (int e = 0; e < 18; e++) {
        Vr[2*e] = vb[e].x; Vi[2*e] = vb[e].y; Vr[2*e+1] = vb[e].z; Vi[2*e+1] = vb[e].w;
        Cr[2*e] = cb[e].x; Ci[2*e] = cb[e].y; Cr[2*e+1] = cb[e].z; Ci[2*e+1] = cb[e].w;
    }

    float Qr[6], Qi[6];
    const float* qrp = Qre_in + (size_t)g * 36 + kk * 6;
    const float* qip = Qim_in + (size_t)g * 36 + kk * 6;
#pragma unroll
    for (int m = 0; m < 6; m++) { Qr[m] = qrp[m]; Qi[m] = qip[m]; }

    if (Sprev) {
        const float sc = Sprev[b] * (1.0f / (float)FMTQ);
        const float s  = rsqrtf(fmaxf(sc, 1e-6f));
#pragma unroll
        for (int m = 0; m < 6; m++) { Qr[m] *= s; Qi[m] *= s; }
    }

#pragma unroll
    for (int k = 0; k < 6; k++) {
        float qr[6], qi[6];
#pragma unroll
        for (int m = 0; m < 6; m++) {
            qr[m] = __shfl(Qr[m], k, 8);
            qi[m] = __shfl(Qi[m], k, 8);
        }
        float Wr[6], Wi[6];
#pragma unroll
        for (int m = 0; m < 6; m++) {
            float wr = 0.0f, wi = 0.0f;
#pragma unroll
            for (int n = 0; n < 6; n++) {
                const float vr = Vr[m * 6 + n], vi = Vi[m * 6 + n];
                wr += vr * qr[n] + vi * qi[n];
                wi += vi * qr[n] - vr * qi[n];
            }
            Wr[m] = wr; Wi[m] = wi;
        }
        float qVq = 0.0f;
#pragma unroll
        for (int m = 0; m < 6; m++) qVq += qr[m] * Wr[m] - qi[m] * Wi[m];
        qVq = fmaxf(qVq, 1e-6f);

        float vr, vi;
        if (kp == k) {
            vr = 1.0f - rsqrtf(qVq);
            vi = 0.0f;
        } else {
            float nr = 0.0f, ni = 0.0f;
#pragma unroll
            for (int m = 0; m < 6; m++) {
                nr += Qr[m] * Wr[m] - Qi[m] * Wi[m];
                ni += Qr[m] * Wi[m] + Qi[m] * Wr[m];
            }
            const float inv = 1.0f / qVq;
            vr = nr * inv; vi = ni * inv;
        }
#pragma unroll
        for (int m = 0; m < 6; m++) {
            Qr[m] -= vr * qr[m] - vi * qi[m];
            Qi[m] -= vr * qi[m] + vi * qr[m];
        }
    }

    float trr = 0.0f;
#pragma unroll
    for (int m = 0; m < 6; m++) {
        float wr = 0.0f, wi = 0.0f;
#pragma unroll
        for (int n = 0; n < 6; n++) {
            const float cr = Cr[m * 6 + n], ci = Ci[m * 6 + n];
            wr += cr * Qr[n] + ci * Qi[n];
            wi += ci * Qr[n] - cr * Qi[n];
        }
        trr += Qr[m] * wr - Qi[m] * wi;
    }
    if (kp >= 6) trr = 0.0f;
    trr += __shfl_xor(trr, 1, 8);
    trr += __shfl_xor(trr, 2, 8);
    trr += __shfl_xor(trr, 4, 8);
    if (kp == 0) atomicAdd(&Sout[b], trr);

    if (kp < 6) {
        float* qro = Qre_out + (size_t)g * 36 + kp * 6;
        float* qio = Qim_out + (size_t)g * 36 + kp * 6;
#pragma unroll
        for (int m = 0; m < 6; m++) { qro[m] = Qr[m]; qio[m] = Qi[m]; }
    }
}

// ---------------------------------------------------------------------------
// K3: xt[m,t] = |Q2 x|^2 / scale2   (float4 over t: 250 cols, 1 per thread)
// + fused Q-output: Q_final = Q2 / sqrt(clip(scale2,1e-6)), planar.
// ---------------------------------------------------------------------------
__global__ __launch_bounds__(256) void k_xt(
    const float* __restrict__ xre, const float* __restrict__ xim,
    const float* __restrict__ Q2r, const float* __restrict__ Q2i,
    const float* __restrict__ S2, float* __restrict__ out,
    float* __restrict__ outQre, float* __restrict__ outQim)
{
    const int bf = blockIdx.x;
    const int b  = bf / FQ;
    const float s2 = S2[b];

    // fused k_qout (threads 0..35 handle this block's 36 Q entries)
    if (threadIdx.x < 36) {
        const float sc = s2 * (1.0f / (float)FMTQ);
        const float s  = rsqrtf(fmaxf(sc, 1e-6f));
        const int j = bf * 36 + (int)threadIdx.x;
        outQre[j] = Q2r[j] * s;
        if (outQim) outQim[j] = Q2i[j] * s;
    }

    const float4* qr4 = reinterpret_cast<const float4*>(Q2r + (size_t)bf * 36);
    const float4* qi4 = reinterpret_cast<const float4*>(Q2i + (size_t)bf * 36);
    float4 qrb[9], qib[9];
#pragma unroll
    for (int e = 0; e < 9; e++) qrb[e] = qr4[e];
#pragma unroll
    for (int e = 0; e < 9; e++) qib[e] = qi4[e];
    float Qr[36], Qi[36];
#pragma unroll
    for (int e = 0; e < 9; e++) {
        Qr[4*e] = qrb[e].x; Qr[4*e+1] = qrb[e].y; Qr[4*e+2] = qrb[e].z; Qr[4*e+3] = qrb[e].w;
        Qi[4*e] = qib[e].x; Qi[4*e+1] = qib[e].y; Qi[4*e+2] = qib[e].z; Qi[4*e+3] = qib[e].w;
    }
    const float inv_scale = (float)FMTQ / s2;

    const int i = threadIdx.x;
    if (i < T4Q) {
        const float4* xr4 = reinterpret_cast<const float4*>(xre + (size_t)bf * MQ * TQ);
        const float4* xi4 = reinterpret_cast<const float4*>(xim + (size_t)bf * MQ * TQ);
        float ar[6][4], ai[6][4];
#pragma unroll
        for (int n = 0; n < 6; n++) {
            const float4 a = xr4[n * T4Q + i];
            ar[n][0] = a.x; ar[n][1] = a.y; ar[n][2] = a.z; ar[n][3] = a.w;
            const float4 c = xi4[n * T4Q + i];
            ai[n][0] = c.x; ai[n][1] = c.y; ai[n][2] = c.z; ai[n][3] = c.w;
        }
        float4* op4 = reinterpret_cast<float4*>(out + (size_t)bf * MQ * TQ);
#pragma unroll
        for (int m = 0; m < 6; m++) {
            float res[4];
#pragma unroll
            for (int e = 0; e < 4; e++) {
                float cr = 0.0f, ci = 0.0f;
#pragma unroll
                for (int n = 0; n < 6; n++) {
                    const float wr = Qr[m * 6 + n], wi = Qi[m * 6 + n];
                    cr += wr * ar[n][e] - wi * ai[n][e];
                    ci += wr * ai[n][e] + wi * ar[n][e];
                }
                res[e] = (cr * cr + ci * ci) * inv_scale;
            }
            op4[m * T4Q + i] = make_float4(res[0], res[1], res[2], res[3]);
        }
    }
}

// ---------------------------------------------------------------------------
extern "C" void kernel_launch(void* const* d_in, const int* in_sizes, int n_in,
                              void* d_out, int out_size, void* d_ws, size_t ws_size,
                              hipStream_t stream)
{
    (void)in_sizes; (void)n_in; (void)ws_size;
    const float* r   = (const float*)d_in[0];
    const float* Qre = (const float*)d_in[1];
    const float* Qim = (const float*)d_in[2];
    const float* xre = (const float*)d_in[3];
    const float* xim = (const float*)d_in[4];

    // workspace layout (floats): V | C | Q1r | Q1i | Q2r | Q2i | S1[16] | S2[16]
    float* ws  = (float*)d_ws;
    float* V   = ws;                          // BFQ*432
    float* Cw  = V   + (size_t)BFQ * 432;     // BFQ*72
    float* Q1r = Cw  + (size_t)BFQ * 72;      // BFQ*36
    float* Q1i = Q1r + (size_t)BFQ * 36;
    float* Q2r = Q1i + (size_t)BFQ * 36;
    float* Q2i = Q2r + (size_t)BFQ * 36;
    float* S1  = Q2i + (size_t)BFQ * 36;      // 16
    float* S2  = S1 + 16;                     // 16

    // Output layout (PLANAR, verified R2): [Q_re plane | Q_im plane | xt]
    const long long xt_elems = (long long)BFQ * MQ * TQ;        // 24,672,000
    const long long q_elems  = (long long)out_size - xt_elems;  // 296,064 or 148,032
    float* out_qre = (float*)d_out;
    float* out_qim = (q_elems >= 2LL * BFQ * 36) ? out_qre + (size_t)BFQ * 36 : nullptr;
    float* out_xt  = out_qre + (size_t)(q_elems > 0 ? q_elems : 2LL * BFQ * 36);

    k_stats<<<BFQ, 256, 0, stream>>>(r, xre, xim, V, Cw, S1);
    const int iterGrid = (BFQ * 8 + 255) / 256;
    k_iter<<<iterGrid, 256, 0, stream>>>(V, Cw, Qre, Qim, nullptr, Q1r, Q1i, S1);
    k_iter<<<iterGrid, 256, 0, stream>>>(V, Cw, Q1r, Q1i, S1, Q2r, Q2i, S2);
    k_xt<<<BFQ, 256, 0, stream>>>(xre, xim, Q2r, Q2i, S2, out_xt, out_qre, out_qim);
}